// Round 1
// baseline (883.735 us; speedup 1.0000x reference)
//
#include <hip/hip_runtime.h>
#include <math.h>

#define NB 64
#define NT 512
#define NVAR 16
#define VDIM 16
#define DD 64
#define FF 256
#define BT (NB*NT)
#define LN_EPS 1e-3f

// cproj[b][n][d] = sum_k ctx[b][k] * Wctx[n][k][d]   (broadcast over T, hoisted)
__global__ void cproj_kernel(const float* __restrict__ ctx,
                             const float* __restrict__ Wctx,
                             float* __restrict__ cproj) {
    int bn = blockIdx.x;
    int b = bn >> 4, n = bn & 15;
    int d = threadIdx.x;
    const float* __restrict__ w = Wctx + n * DD * DD;
    const float* __restrict__ c = ctx + b * DD;
    float acc = 0.f;
    #pragma unroll 8
    for (int k = 0; k < DD; ++k)
        acc += c[k] * w[k * DD + d];
    cproj[bn * DD + d] = acc;
}

// Main kernel: block = 256 threads = 4 waves. Wave w handles 64 tokens
// (lane = token) x 4 variables (vars w*4..w*4+3). GEMV weights are
// lane-uniform (scalarizable); per-token intermediates round-trip through a
// per-wave 16KB LDS buffer with XOR bank swizzle (conflict-free b32).
__global__ __launch_bounds__(256, 2)
void vsn_kernel(const float* __restrict__ inp,
                const float* __restrict__ Wt, const float* __restrict__ bt,
                const float* __restrict__ W1, const float* __restrict__ b1,
                const float* __restrict__ W2, const float* __restrict__ b2,
                const float* __restrict__ Wg, const float* __restrict__ bg,
                const float* __restrict__ Wp, const float* __restrict__ bp,
                const float* __restrict__ gamma_, const float* __restrict__ beta_,
                const float* __restrict__ Ws, const float* __restrict__ bs,
                const float* __restrict__ cproj,
                float* __restrict__ out_sel, float* __restrict__ out_w) {

    __shared__ float s_buf[4][DD * DD];   // 64KB: per-wave scratch, row=token, col xor-swizzled
    __shared__ float s_sel[DD * DD];      // 16KB: [d][tok ^ (d&31)], selection accumulator

    const int tid   = threadIdx.x;
    const int lane  = tid & 63;
    const int wv    = __builtin_amdgcn_readfirstlane(tid >> 6);
    const int tile0 = blockIdx.x * 64;                       // 64 tokens per block, same b
    const int b     = __builtin_amdgcn_readfirstlane(blockIdx.x >> 3);  // tile0 / NT

    float* buf = &s_buf[wv][0];
    const int swl = lane & 31;

    // zero selection accumulator
    for (int i = tid; i < DD * DD; i += 256) s_sel[i] = 0.f;
    __syncthreads();

    // ---------------- logits + softmax (each wave computes full softmax) ----
    float lg[16];
    #pragma unroll
    for (int n = 0; n < 16; ++n) lg[n] = bs[n];

    for (int c = 0; c < 16; ++c) {
        // stage 64 tokens x 16 floats (feature cols c*16..c*16+15)
        #pragma unroll
        for (int j = 0; j < 4; ++j) {
            int idx = j * 64 + lane;
            int tok = idx >> 2, f4 = (idx & 3) * 4;
            float4 v = *(const float4*)(inp + (tile0 + tok) * FF + c * VDIM + f4);
            int sw = tok & 31;
            buf[tok * 64 + ((f4 + 0) ^ sw)] = v.x;
            buf[tok * 64 + ((f4 + 1) ^ sw)] = v.y;
            buf[tok * 64 + ((f4 + 2) ^ sw)] = v.z;
            buf[tok * 64 + ((f4 + 3) ^ sw)] = v.w;
        }
        // wave-private buffer: no __syncthreads needed (in-order DS per wave)
        #pragma unroll 2
        for (int k = 0; k < 16; ++k) {
            float xk = buf[lane * 64 + (k ^ swl)];
            const float* __restrict__ wsrow = Ws + (c * 16 + k) * 16;
            #pragma unroll
            for (int n = 0; n < 16; ++n) lg[n] += xk * wsrow[n];
        }
    }
    float mx = lg[0];
    #pragma unroll
    for (int n = 1; n < 16; ++n) mx = fmaxf(mx, lg[n]);
    float w[16];
    float sum = 0.f;
    #pragma unroll
    for (int n = 0; n < 16; ++n) { w[n] = __expf(lg[n] - mx); sum += w[n]; }
    float rsum = 1.f / sum;
    #pragma unroll
    for (int n = 0; n < 16; ++n) w[n] *= rsum;

    if (wv == 0) {
        #pragma unroll
        for (int n = 0; n < 16; ++n)
            out_w[(tile0 + lane) * 16 + n] = w[n];
    }

    // ---------------- per-variable GRN chain (4 vars per wave) --------------
    for (int vi = 0; vi < 4; ++vi) {
        const int n = wv * 4 + vi;
        const float* __restrict__ pwt = Wt + n * VDIM * DD;
        const float* __restrict__ pw1 = W1 + n * DD * DD;
        const float* __restrict__ pw2 = W2 + n * DD * DD;
        const float* __restrict__ pwg = Wg + n * DD * DD;
        const float* __restrict__ pwp = Wp + n * DD * DD;
        const float* __restrict__ pcp = cproj + (b * NVAR + n) * DD;

        // stage xv[:, n*16 .. n*16+15] into buf cols 0..15
        #pragma unroll
        for (int j = 0; j < 4; ++j) {
            int idx = j * 64 + lane;
            int tok = idx >> 2, f4 = (idx & 3) * 4;
            float4 v = *(const float4*)(inp + (tile0 + tok) * FF + n * VDIM + f4);
            int sw = tok & 31;
            buf[tok * 64 + ((f4 + 0) ^ sw)] = v.x;
            buf[tok * 64 + ((f4 + 1) ^ sw)] = v.y;
            buf[tok * 64 + ((f4 + 2) ^ sw)] = v.z;
            buf[tok * 64 + ((f4 + 3) ^ sw)] = v.w;
        }

        // t = xv @ Wt + bt
        float acc[64];
        #pragma unroll
        for (int d = 0; d < 64; ++d) acc[d] = bt[n * DD + d];
        #pragma unroll 2
        for (int k = 0; k < VDIM; ++k) {
            float xk = buf[lane * 64 + (k ^ swl)];
            const float* __restrict__ wr = pwt + k * DD;
            #pragma unroll
            for (int d = 0; d < 64; ++d) acc[d] += xk * wr[d];
        }
        #pragma unroll
        for (int d = 0; d < 64; ++d) buf[lane * 64 + (d ^ swl)] = acc[d];  // t -> buf

        // residual = t @ Wp + bp  (kept in VGPRs)
        float res[64];
        #pragma unroll
        for (int d = 0; d < 64; ++d) res[d] = bp[n * DD + d];
        #pragma unroll 2
        for (int k = 0; k < 64; ++k) {
            float tk = buf[lane * 64 + (k ^ swl)];
            const float* __restrict__ wr = pwp + k * DD;
            #pragma unroll
            for (int d = 0; d < 64; ++d) res[d] += tk * wr[d];
        }

        // h1 = elu((t + cproj) @ W1 + b1)
        #pragma unroll
        for (int d = 0; d < 64; ++d) acc[d] = b1[n * DD + d];
        #pragma unroll 2
        for (int k = 0; k < 64; ++k) {
            float ak = buf[lane * 64 + (k ^ swl)] + pcp[k];
            const float* __restrict__ wr = pw1 + k * DD;
            #pragma unroll
            for (int d = 0; d < 64; ++d) acc[d] += ak * wr[d];
        }
        #pragma unroll
        for (int d = 0; d < 64; ++d)
            acc[d] = acc[d] > 0.f ? acc[d] : (__expf(acc[d]) - 1.f);
        #pragma unroll
        for (int d = 0; d < 64; ++d) buf[lane * 64 + (d ^ swl)] = acc[d];  // h1 -> buf

        // h2 = h1 @ W2 + b2   (kept in VGPRs for the gate product)
        float h2[64];
        #pragma unroll
        for (int d = 0; d < 64; ++d) h2[d] = b2[n * DD + d];
        #pragma unroll 2
        for (int k = 0; k < 64; ++k) {
            float hk = buf[lane * 64 + (k ^ swl)];
            const float* __restrict__ wr = pw2 + k * DD;
            #pragma unroll
            for (int d = 0; d < 64; ++d) h2[d] += hk * wr[d];
        }
        #pragma unroll
        for (int d = 0; d < 64; ++d) buf[lane * 64 + (d ^ swl)] = h2[d];   // h2 -> buf

        // gate = sigmoid(h2 @ Wg + bg)
        #pragma unroll
        for (int d = 0; d < 64; ++d) acc[d] = bg[n * DD + d];
        #pragma unroll 2
        for (int k = 0; k < 64; ++k) {
            float hk = buf[lane * 64 + (k ^ swl)];
            const float* __restrict__ wr = pwg + k * DD;
            #pragma unroll
            for (int d = 0; d < 64; ++d) acc[d] += hk * wr[d];
        }

        // z = sigmoid(g)*h2 + res ; LayerNorm (in-lane over 64 regs) ; select
        float mu = 0.f;
        #pragma unroll
        for (int d = 0; d < 64; ++d) {
            float g = 1.f / (1.f + __expf(-acc[d]));
            acc[d] = g * h2[d] + res[d];
            mu += acc[d];
        }
        mu *= (1.f / 64.f);
        float var = 0.f;
        #pragma unroll
        for (int d = 0; d < 64; ++d) { acc[d] -= mu; var += acc[d] * acc[d]; }
        float rstd = rsqrtf(var * (1.f / 64.f) + LN_EPS);
        const float wn = w[n];
        #pragma unroll
        for (int d = 0; d < 64; ++d) {
            float y = acc[d] * rstd * gamma_[n * DD + d] + beta_[n * DD + d];
            atomicAdd(&s_sel[d * 64 + (lane ^ (d & 31))], wn * y);
        }
    }

    __syncthreads();

    // write selected: coalesced, conflict-free via swizzle
    #pragma unroll
    for (int i = 0; i < 16; ++i) {
        int tok = i * 4 + (tid >> 6);
        int d = tid & 63;
        out_sel[(tile0 + tok) * DD + d] = s_sel[d * 64 + (tok ^ (d & 31))];
    }
}

extern "C" void kernel_launch(void* const* d_in, const int* in_sizes, int n_in,
                              void* d_out, int out_size, void* d_ws, size_t ws_size,
                              hipStream_t stream) {
    const float* inp  = (const float*)d_in[0];
    const float* ctx  = (const float*)d_in[1];
    const float* Wt   = (const float*)d_in[2];
    const float* bt   = (const float*)d_in[3];
    const float* Wctx = (const float*)d_in[4];
    const float* W1   = (const float*)d_in[5];
    const float* b1   = (const float*)d_in[6];
    const float* W2   = (const float*)d_in[7];
    const float* b2   = (const float*)d_in[8];
    const float* Wg   = (const float*)d_in[9];
    const float* bg   = (const float*)d_in[10];
    const float* Wp   = (const float*)d_in[11];
    const float* bp   = (const float*)d_in[12];
    const float* gm   = (const float*)d_in[13];
    const float* bt2  = (const float*)d_in[14];
    const float* Ws   = (const float*)d_in[15];
    const float* bs   = (const float*)d_in[16];

    float* out_sel = (float*)d_out;
    float* out_w   = out_sel + (size_t)BT * DD;
    float* cproj   = (float*)d_ws;   // 64*16*64 floats = 256KB

    cproj_kernel<<<NB * NVAR, DD, 0, stream>>>(ctx, Wctx, cproj);
    vsn_kernel<<<BT / 64, 256, 0, stream>>>(inp, Wt, bt, W1, b1, W2, b2,
                                            Wg, bg, Wp, bp, gm, bt2, Ws, bs,
                                            cproj, out_sel, out_w);
}

// Round 2
// 856.666 us; speedup vs baseline: 1.0316x; 1.0316x over previous
//
#include <hip/hip_runtime.h>
#include <math.h>

#define NB 64
#define NT 512
#define NVAR 16
#define VDIM 16
#define DD 64
#define FF 256
#define BT (NB*NT)
#define LN_EPS 1e-3f

// cproj[b][n][d] = sum_k ctx[b][k] * Wctx[n][k][d]   (broadcast over T, hoisted)
__global__ void cproj_kernel(const float* __restrict__ ctx,
                             const float* __restrict__ Wctx,
                             float* __restrict__ cproj) {
    int bn = blockIdx.x;
    int b = bn >> 4, n = bn & 15;
    int d = threadIdx.x;
    const float* __restrict__ w = Wctx + n * DD * DD;
    const float* __restrict__ c = ctx + b * DD;
    float acc = 0.f;
    #pragma unroll 8
    for (int k = 0; k < DD; ++k)
        acc += c[k] * w[k * DD + d];
    cproj[bn * DD + d] = acc;
}

// Block = 256 threads = 4 waves. Wave w: lane = token (64 tokens/block),
// vars w*4..w*4+3. Weights are wave-uniform loads; per-token intermediates
// round-trip a per-wave 16KB LDS buffer (XOR swizzle, conflict-free b32).
// Register discipline: max live = res[64] + 32-wide acc half + 2x32 weights
// (#pragma unroll 2). No dynamic indexing of register arrays.
__global__ __launch_bounds__(256, 2)
void vsn_kernel(const float* __restrict__ inp,
                const float* __restrict__ Wt, const float* __restrict__ bt,
                const float* __restrict__ W1, const float* __restrict__ b1,
                const float* __restrict__ W2, const float* __restrict__ b2,
                const float* __restrict__ Wg, const float* __restrict__ bg,
                const float* __restrict__ Wp, const float* __restrict__ bp,
                const float* __restrict__ gamma_, const float* __restrict__ beta_,
                const float* __restrict__ Ws, const float* __restrict__ bs,
                const float* __restrict__ cproj,
                float* __restrict__ out_sel, float* __restrict__ out_w) {

    __shared__ float s_buf[4][DD * DD];   // 64KB per-wave scratch (row=token, xor-swizzled cols)
    __shared__ float s_sel[DD * DD];      // 16KB selection accumulator [d][tok ^ (d&31)]

    const int tid   = threadIdx.x;
    const int lane  = tid & 63;
    const int wv    = __builtin_amdgcn_readfirstlane(tid >> 6);
    const int tile0 = blockIdx.x * 64;
    const int b     = blockIdx.x >> 3;     // tile0 / NT

    float* buf = &s_buf[wv][0];
    const int swl = lane & 31;
    const int rowb = lane * 64;

    for (int i = tid; i < DD * DD; i += 256) s_sel[i] = 0.f;
    __syncthreads();

    // ---------------- logits + softmax (each wave computes full softmax) ----
    float lg[16];
    #pragma unroll
    for (int n = 0; n < 16; ++n) lg[n] = bs[n];

    for (int c = 0; c < 16; ++c) {
        #pragma unroll
        for (int j = 0; j < 4; ++j) {
            int idx = j * 64 + lane;
            int tok = idx >> 2, f4 = (idx & 3) * 4;
            float4 v = *(const float4*)(inp + (tile0 + tok) * FF + c * VDIM + f4);
            int sw = tok & 31;
            buf[tok * 64 + ((f4 + 0) ^ sw)] = v.x;
            buf[tok * 64 + ((f4 + 1) ^ sw)] = v.y;
            buf[tok * 64 + ((f4 + 2) ^ sw)] = v.z;
            buf[tok * 64 + ((f4 + 3) ^ sw)] = v.w;
        }
        #pragma unroll 2
        for (int k = 0; k < 16; ++k) {
            float xk = buf[rowb + (k ^ swl)];
            const float* __restrict__ wsrow = Ws + (c * 16 + k) * 16;
            #pragma unroll
            for (int n = 0; n < 16; ++n) lg[n] += xk * wsrow[n];
        }
    }
    float mx = lg[0];
    #pragma unroll
    for (int n = 1; n < 16; ++n) mx = fmaxf(mx, lg[n]);
    float w[16];
    float sum = 0.f;
    #pragma unroll
    for (int n = 0; n < 16; ++n) { w[n] = __expf(lg[n] - mx); sum += w[n]; }
    float rsum = 1.f / sum;
    #pragma unroll
    for (int n = 0; n < 16; ++n) w[n] *= rsum;

    if (wv == 0) {
        #pragma unroll
        for (int n = 0; n < 16; ++n)
            out_w[(tile0 + lane) * 16 + n] = w[n];
    }

    // Extract this wave's 4 selection weights with CONSTANT register indices
    // (dynamic w[wv*4+vi] would force the array to scratch).
    float wsel0, wsel1, wsel2, wsel3;
    if (wv == 0)      { wsel0 = w[0];  wsel1 = w[1];  wsel2 = w[2];  wsel3 = w[3];  }
    else if (wv == 1) { wsel0 = w[4];  wsel1 = w[5];  wsel2 = w[6];  wsel3 = w[7];  }
    else if (wv == 2) { wsel0 = w[8];  wsel1 = w[9];  wsel2 = w[10]; wsel3 = w[11]; }
    else              { wsel0 = w[12]; wsel1 = w[13]; wsel2 = w[14]; wsel3 = w[15]; }

    // ---------------- per-variable GRN chain (4 vars per wave) --------------
    for (int vi = 0; vi < 4; ++vi) {
        const int n = wv * 4 + vi;
        const float wn = (vi == 0) ? wsel0 : (vi == 1) ? wsel1 : (vi == 2) ? wsel2 : wsel3;
        const float* __restrict__ pwt = Wt + n * VDIM * DD;
        const float* __restrict__ pw1 = W1 + n * DD * DD;
        const float* __restrict__ pw2 = W2 + n * DD * DD;
        const float* __restrict__ pwg = Wg + n * DD * DD;
        const float* __restrict__ pwp = Wp + n * DD * DD;
        const float* __restrict__ pcp = cproj + (b * NVAR + n) * DD;

        // stage xv[:, n*16 .. n*16+15]
        #pragma unroll
        for (int j = 0; j < 4; ++j) {
            int idx = j * 64 + lane;
            int tok = idx >> 2, f4 = (idx & 3) * 4;
            float4 v = *(const float4*)(inp + (tile0 + tok) * FF + n * VDIM + f4);
            int sw = tok & 31;
            buf[tok * 64 + ((f4 + 0) ^ sw)] = v.x;
            buf[tok * 64 + ((f4 + 1) ^ sw)] = v.y;
            buf[tok * 64 + ((f4 + 2) ^ sw)] = v.z;
            buf[tok * 64 + ((f4 + 3) ^ sw)] = v.w;
        }

        // ---- t = xv @ Wt + bt  (full 64-wide; only acc live) ----
        {
            float acc[64];
            #pragma unroll
            for (int d = 0; d < 64; ++d) acc[d] = bt[n * DD + d];
            #pragma unroll 2
            for (int k = 0; k < VDIM; ++k) {
                float xk = buf[rowb + (k ^ swl)];
                const float* __restrict__ wr = pwt + k * DD;
                #pragma unroll
                for (int d = 0; d < 64; ++d) acc[d] += xk * wr[d];
            }
            #pragma unroll
            for (int d = 0; d < 64; ++d) buf[rowb + (d ^ swl)] = acc[d];   // t -> buf
        }

        // ---- res = t @ Wp + bp  (full 64-wide; res stays live to the end) --
        float res[64];
        #pragma unroll
        for (int d = 0; d < 64; ++d) res[d] = bp[n * DD + d];
        #pragma unroll 2
        for (int k = 0; k < 64; ++k) {
            float tk = buf[rowb + (k ^ swl)];
            const float* __restrict__ wr = pwp + k * DD;
            #pragma unroll
            for (int d = 0; d < 64; ++d) res[d] += tk * wr[d];
        }

        // ---- h1 = elu((t+cproj) @ W1 + b1), 32-wide halves kept in regs ----
        {
            float ha[32], hb[32];
            #pragma unroll
            for (int dh = 0; dh < 2; ++dh) {
                float* hh = dh ? hb : ha;
                #pragma unroll
                for (int d = 0; d < 32; ++d) hh[d] = b1[n * DD + dh * 32 + d];
                #pragma unroll 2
                for (int k = 0; k < 64; ++k) {
                    float ak = buf[rowb + (k ^ swl)] + pcp[k];
                    const float* __restrict__ wr = pw1 + k * DD + dh * 32;
                    #pragma unroll
                    for (int d = 0; d < 32; ++d) hh[d] += ak * wr[d];
                }
                #pragma unroll
                for (int d = 0; d < 32; ++d)
                    hh[d] = hh[d] > 0.f ? hh[d] : (__expf(hh[d]) - 1.f);
            }
            #pragma unroll
            for (int d = 0; d < 32; ++d) {
                buf[rowb + (d ^ swl)] = ha[d];
                buf[rowb + ((d + 32) ^ swl)] = hb[d];
            }
        }

        // ---- h2 = h1 @ W2 + b2, halves in regs, then -> buf ----
        {
            float ha[32], hb[32];
            #pragma unroll
            for (int dh = 0; dh < 2; ++dh) {
                float* hh = dh ? hb : ha;
                #pragma unroll
                for (int d = 0; d < 32; ++d) hh[d] = b2[n * DD + dh * 32 + d];
                #pragma unroll 2
                for (int k = 0; k < 64; ++k) {
                    float hk = buf[rowb + (k ^ swl)];
                    const float* __restrict__ wr = pw2 + k * DD + dh * 32;
                    #pragma unroll
                    for (int d = 0; d < 32; ++d) hh[d] += hk * wr[d];
                }
            }
            #pragma unroll
            for (int d = 0; d < 32; ++d) {
                buf[rowb + (d ^ swl)] = ha[d];
                buf[rowb + ((d + 32) ^ swl)] = hb[d];
            }
        }

        // ---- gate + z, 32-wide halves; h2 read back from buf per element ---
        float z[64];
        #pragma unroll
        for (int dh = 0; dh < 2; ++dh) {
            float g[32];
            #pragma unroll
            for (int d = 0; d < 32; ++d) g[d] = bg[n * DD + dh * 32 + d];
            #pragma unroll 2
            for (int k = 0; k < 64; ++k) {
                float hk = buf[rowb + (k ^ swl)];
                const float* __restrict__ wr = pwg + k * DD + dh * 32;
                #pragma unroll
                for (int d = 0; d < 32; ++d) g[d] += hk * wr[d];
            }
            #pragma unroll
            for (int d = 0; d < 32; ++d) {
                float h2d = buf[rowb + ((dh * 32 + d) ^ swl)];
                float gd = 1.f / (1.f + __expf(-g[d]));
                z[dh * 32 + d] = gd * h2d + res[d + dh * 32];
            }
        }

        // ---- LayerNorm over the 64 in-lane values + weighted selection ----
        float mu = 0.f;
        #pragma unroll
        for (int d = 0; d < 64; ++d) mu += z[d];
        mu *= (1.f / 64.f);
        float var = 0.f;
        #pragma unroll
        for (int d = 0; d < 64; ++d) { z[d] -= mu; var += z[d] * z[d]; }
        float rstd = rsqrtf(var * (1.f / 64.f) + LN_EPS);
        #pragma unroll
        for (int d = 0; d < 64; ++d) {
            float y = z[d] * rstd * gamma_[n * DD + d] + beta_[n * DD + d];
            atomicAdd(&s_sel[d * 64 + (lane ^ (d & 31))], wn * y);
        }
    }

    __syncthreads();

    #pragma unroll
    for (int i = 0; i < 16; ++i) {
        int tok = i * 4 + (tid >> 6);
        int d = tid & 63;
        out_sel[(tile0 + tok) * DD + d] = s_sel[d * 64 + (tok ^ (d & 31))];
    }
}

extern "C" void kernel_launch(void* const* d_in, const int* in_sizes, int n_in,
                              void* d_out, int out_size, void* d_ws, size_t ws_size,
                              hipStream_t stream) {
    const float* inp  = (const float*)d_in[0];
    const float* ctx  = (const float*)d_in[1];
    const float* Wt   = (const float*)d_in[2];
    const float* bt   = (const float*)d_in[3];
    const float* Wctx = (const float*)d_in[4];
    const float* W1   = (const float*)d_in[5];
    const float* b1   = (const float*)d_in[6];
    const float* W2   = (const float*)d_in[7];
    const float* b2   = (const float*)d_in[8];
    const float* Wg   = (const float*)d_in[9];
    const float* bg   = (const float*)d_in[10];
    const float* Wp   = (const float*)d_in[11];
    const float* bp   = (const float*)d_in[12];
    const float* gm   = (const float*)d_in[13];
    const float* bt2  = (const float*)d_in[14];
    const float* Ws   = (const float*)d_in[15];
    const float* bs   = (const float*)d_in[16];

    float* out_sel = (float*)d_out;
    float* out_w   = out_sel + (size_t)BT * DD;
    float* cproj   = (float*)d_ws;   // 64*16*64 floats = 256KB

    cproj_kernel<<<NB * NVAR, DD, 0, stream>>>(ctx, Wctx, cproj);
    vsn_kernel<<<BT / 64, 256, 0, stream>>>(inp, Wt, bt, W1, b1, W2, b2,
                                            Wg, bg, Wp, bp, gm, bt2, Ws, bs,
                                            cproj, out_sel, out_w);
}